// Round 16
// baseline (165.683 us; speedup 1.0000x reference)
//
#include <hip/hip_runtime.h>
#include <cmath>

typedef unsigned int u32;
typedef unsigned long long u64;
typedef unsigned char u8;
typedef unsigned short u16;
typedef float f32x4 __attribute__((ext_vector_type(4)));

#define GS 33  // coarse-prefix group size (rem <= 32 fits one wave's lanes 0..31)

// Marching-tets tables from the reference
__constant__ signed char c_tri[16][6] = {
    {-1,-1,-1,-1,-1,-1},
    { 1, 0, 2,-1,-1,-1},
    { 4, 0, 3,-1,-1,-1},
    { 1, 4, 2, 1, 3, 4},
    { 3, 1, 5,-1,-1,-1},
    { 2, 3, 0, 2, 5, 3},
    { 1, 4, 0, 1, 5, 4},
    { 4, 2, 5,-1,-1,-1},
    { 4, 5, 2,-1,-1,-1},
    { 4, 1, 0, 4, 5, 1},
    { 3, 2, 0, 3, 5, 2},
    { 1, 3, 5,-1,-1,-1},
    { 4, 1, 2, 4, 3, 1},
    { 3, 0, 4,-1,-1,-1},
    { 2, 0, 1,-1,-1,-1},
    {-1,-1,-1,-1,-1,-1}};
__constant__ signed char c_ntri[16] = {0,1,1,2,1,2,2,1,1,2,2,1,2,1,1,0};
__constant__ signed char c_edge_p[6] = {0,0,0,1,1,2};
__constant__ signed char c_edge_q[6] = {1,2,3,2,3,3};
// 6-tet decomposition of a cube around the 0-7 diagonal (corner n: bit0=dx,bit1=dy,bit2=dz)
__constant__ u8 c_six[6][4] = {{0,5,1,7},{0,1,3,7},{0,3,2,7},{0,2,6,7},{0,6,4,7},{0,4,5,7}};

// ---- fused pass: mask + occ + cube counts + intra-block prefix (pfx16) ----
// (verified round 9/10) NO grand-total atomics (round-5 lesson).
__global__ void k_main(const float* __restrict__ sdf, u8* __restrict__ vmask,
                       u16* __restrict__ pfx16, u32* __restrict__ vbsums,
                       u32* __restrict__ cbsums, int Nv, int V, int G) {
    int v = blockIdx.x * 256 + threadIdx.x;
    u32 cnt = 0, pack = 0;
    if (v < Nv) {
        int x = v % V;
        int t = v / V;
        int y = t % V;
        int z = t / V;
        const int V2 = V * V;
        float s0 = sdf[v];
        bool occ0 = s0 > 0.0f;
        bool bx = x < G, by = y < G, bz = z < G;
        int  d[7]  = {1, V, V + 1, V2, V2 + 1, V2 + V, V2 + V + 1};
        bool ok[7] = {bx, by, bx && by, bz, bx && bz, by && bz, bx && by && bz};
        u32 m = 0;
        u32 occ8 = occ0 ? 1u : 0u;
#pragma unroll
        for (int k = 0; k < 7; ++k) {
            if (ok[k]) {
                bool o1 = sdf[v + d[k]] > 0.0f;
                occ8 |= (u32)o1 << (k + 1);
                if (o1 != occ0) m |= (1u << k);
            }
        }
        vmask[v] = (u8)(m | (occ0 ? 0x80u : 0u));
        cnt = __popc(m);
        if (bx && by && bz) {
            u32 c1 = 0, c2 = 0;
#pragma unroll
            for (int w = 0; w < 6; ++w) {
                int ti = ((occ8 >> c_six[w][0]) & 1) | (((occ8 >> c_six[w][1]) & 1) << 1) |
                         (((occ8 >> c_six[w][2]) & 1) << 2) | (((occ8 >> c_six[w][3]) & 1) << 3);
                int nt = c_ntri[ti];
                c1 += (nt == 1);
                c2 += (nt == 2);
            }
            pack = c1 | (c2 << 16);
        }
    }
    int lane = threadIdx.x & 63, wid = threadIdx.x >> 6;
    u32 s = cnt, sp = pack;
#pragma unroll
    for (int o = 1; o < 64; o <<= 1) {
        u32 t = __shfl_up(s, o, 64);
        u32 tp = __shfl_up(sp, o, 64);
        if (lane >= o) { s += t; sp += tp; }
    }
    __shared__ u32 wsum[4], wpk[4];
    if (lane == 63) { wsum[wid] = s; wpk[wid] = sp; }
    __syncthreads();
    u32 wb = 0;
#pragma unroll
    for (int k = 0; k < 4; ++k)
        if (k < wid) wb += wsum[k];
    if (v < Nv) pfx16[v] = (u16)(wb + s - cnt);
    if (threadIdx.x == 0) {
        vbsums[blockIdx.x] = wsum[0] + wsum[1] + wsum[2] + wsum[3];
        cbsums[blockIdx.x] = wpk[0] + wpk[1] + wpk[2] + wpk[3];
    }
}

// ---- k_mid: 1 block — grand totals + coarse exclusive prefixes ------------
// Replaces the 2-block scan kernel (~10-12us serial bubble). coarseV[g] =
// sum vbsums[0..g*GS); coarseC[g] = split-u64 prefix of cbsums. Tail blocks
// self-derive exact prefixes with one coarse lookup + <=32-lane reduce.
__global__ void k_mid(const u32* __restrict__ vbsums, const u32* __restrict__ cbsums,
                      int nbV, u32* __restrict__ coarseV, u64* __restrict__ coarseC,
                      u32* __restrict__ totals) {
    int tid = threadIdx.x;
    int lane = tid & 63, wid = tid >> 6;  // 1024 thr: wid 0..15
    int NG = (nbV + GS - 1) / GS;
    u32 gv = 0;
    u64 gc = 0;
    if (tid < NG) {
        int s0 = tid * GS;
        int e0 = s0 + GS;
        if (e0 > nbV) e0 = nbV;
        for (int i = s0; i < e0; ++i) {
            gv += vbsums[i];
            u32 rc = cbsums[i];
            gc += (u64)(rc & 0xFFFFu) | ((u64)(rc >> 16) << 32);
        }
    }
    u32 v = gv;
    u64 c = gc;
#pragma unroll
    for (int o = 1; o < 64; o <<= 1) {
        u32 tv = __shfl_up(v, o, 64);
        u64 tc = __shfl_up(c, o, 64);
        if (lane >= o) { v += tv; c += tc; }
    }
    __shared__ u32 wsV[16];
    __shared__ u64 wsC[16];
    if (lane == 63) { wsV[wid] = v; wsC[wid] = c; }
    __syncthreads();
    if (wid == 0) {
        u32 wv = (lane < 16) ? wsV[lane] : 0u;
        u64 wc = (lane < 16) ? wsC[lane] : 0ull;
#pragma unroll
        for (int o = 1; o < 16; o <<= 1) {
            u32 tv = __shfl_up(wv, o, 64);
            u64 tc = __shfl_up(wc, o, 64);
            if (lane >= o) { wv += tv; wc += tc; }
        }
        if (lane < 16) { wsV[lane] = wv; wsC[lane] = wc; }
    }
    __syncthreads();
    u32 ebv = (wid ? wsV[wid - 1] : 0u) + v - gv;
    u64 ebc = (wid ? wsC[wid - 1] : 0ull) + c - gc;
    if (tid < NG) { coarseV[tid] = ebv; coarseC[tid] = ebc; }
    if (tid == NG - 1) {
        totals[0] = ebv + gv;                  // E
        u64 tc = ebc + gc;
        totals[1] = (u32)(tc & 0xFFFFFFFFull); // Tm1
        totals[2] = (u32)(tc >> 32);           // Tm2
    }
}

// ---- exact exclusive prefix of vbsums up to block k (coarse + fine) -------
__device__ inline u32 vpfx_wave(const u32* __restrict__ vbsums,
                                const u32* __restrict__ coarseV, int k, int ln) {
    int g0 = k / GS;
    int rem = k - g0 * GS;  // 0..GS-1 <= 32
    u32 part = (ln < rem) ? vbsums[g0 * GS + ln] : 0u;
#pragma unroll
    for (int o = 32; o > 0; o >>= 1) part += __shfl_down(part, o, 64);
    u32 r = coarseV[g0] + part;  // valid in lane 0
    return r;
}

// ---- uvs element helper (head/tail scalar path) ---------------------------
__device__ inline float uv_elem(long long e, int Nuv, double invN, double step_d,
                                float pad, float last) {
    int p = (int)(e >> 3);
    int i = (int)((double)p * invN);
    int j = p - i * Nuv;
    if (j >= Nuv) { j -= Nuv; ++i; }
    int r = (int)(e & 7);
    int c = r >> 1;
    if ((r & 1) == 0) {
        float tx = (j == Nuv - 1) ? last : (float)((double)j * step_d);
        return tx + ((c == 1 || c == 2) ? pad : 0.0f);
    }
    float ty = (i == Nuv - 1) ? last : (float)((double)i * step_d);
    return ty + ((c >= 2) ? pad : 0.0f);
}

// ---- TAIL (R10 verified mapping + uvs body; front blocks self-derive their
// prefixes from raw vbsums/cbsums + coarse tables — no scan kernel) ---------
__global__ void k_tail(const float* __restrict__ sdf, const u8* __restrict__ vmask,
                       const u16* __restrict__ pfx16, const u32* __restrict__ vbsums,
                       const u32* __restrict__ cbsums, const u32* __restrict__ coarseV,
                       const u64* __restrict__ coarseC, const u32* __restrict__ totals,
                       float* __restrict__ out, int Nv, int V, int G, int nbV,
                       float h, int Nuv, double invN, double step_d, float pad,
                       float last, long long npts2) {
    int tid = threadIdx.x;
    int b0 = blockIdx.x;
    int nfront = 2 * nbV;
    int fidx = -1;
    if (b0 % 6 == 0) {
        int f = b0 / 6;
        if (f < nfront) fidx = f;
    }
    if (fidx >= 0 && fidx < nbV) {
        // ---------------- faces + uv_idx ----------------------------------
        int b = fidx;
        int v = b * 256 + tid;
        const int V2 = V * V;
        u32 pack = 0, occ8 = 0;
        int x = 0, y = 0, z = 0;
        bool interior = false;
        if (v < Nv) {
            x = v % V;
            int t = v / V;
            y = t % V;
            z = t / V;
            interior = (x < G) && (y < G) && (z < G);
        }
        const int off[8] = {0, 1, V, V + 1, V2, V2 + 1, V2 + V, V2 + V + 1};
        if (interior) {
#pragma unroll
            for (int n = 0; n < 8; ++n) occ8 |= (u32)(vmask[v + off[n]] >> 7) << n;
            u32 c1 = 0, c2 = 0;
#pragma unroll
            for (int w = 0; w < 6; ++w) {
                int ti = ((occ8 >> c_six[w][0]) & 1) | (((occ8 >> c_six[w][1]) & 1) << 1) |
                         (((occ8 >> c_six[w][2]) & 1) << 2) | (((occ8 >> c_six[w][3]) & 1) << 3);
                int nt = c_ntri[ti];
                c1 += (nt == 1);
                c2 += (nt == 2);
            }
            pack = c1 | (c2 << 16);
        }
        int lane = tid & 63, wid = tid >> 6;
        u32 s = pack;
#pragma unroll
        for (int o = 1; o < 64; o <<= 1) {
            u32 t = __shfl_up(s, o, 64);
            if (lane >= o) s += t;
        }
        __shared__ u32 wsum[4];
        if (lane == 63) wsum[wid] = s;
        __syncthreads();
        u32 wb = 0;
#pragma unroll
        for (int k = 0; k < 4; ++k)
            if (k < wid) wb += wsum[k];
        u32 excl = wb + s - pack;

        // cooperative prefix derivation (all waves participate, before exits)
        // lonode>>8 - b is in {0, 1, K, K+1, K+2}, K = V2>>8 (interval analysis)
        __shared__ u32 sh_vpfx[5];
        __shared__ u32 sh_bo_lo, sh_bo_hi;
        int K = V2 >> 8;
        if (wid < 4) {
            int koff = (wid == 0) ? 0 : (wid == 1) ? 1 : (wid == 2) ? K : K + 1;
            int k = b + koff;
            u32 r = 0;
            if (k < nbV) r = vpfx_wave(vbsums, coarseV, k, lane);
            if (lane == 0) sh_vpfx[wid] = r;
            if (wid == 3) {  // also K+2
                int k2 = b + K + 2;
                u32 r2 = 0;
                if (k2 < nbV) r2 = vpfx_wave(vbsums, coarseV, k2, lane);
                if (lane == 0) sh_vpfx[4] = r2;
            }
            if (wid == 0) {  // cbsums prefix at b (split u64)
                int g0 = b / GS;
                int rem = b - g0 * GS;
                u32 rc = (lane < rem) ? cbsums[g0 * GS + lane] : 0u;
                u64 part = (u64)(rc & 0xFFFFu) | ((u64)(rc >> 16) << 32);
#pragma unroll
                for (int o = 32; o > 0; o >>= 1) part += __shfl_down(part, o, 64);
                if (lane == 0) {
                    u64 bo = coarseC[g0] + part;
                    sh_bo_lo = (u32)(bo & 0xFFFFFFFFull);
                    sh_bo_hi = (u32)(bo >> 32);
                }
            }
        }
        __syncthreads();
        if (!interior || pack == 0) return;

        u32 m1pos = sh_bo_lo + (excl & 0xFFFFu);
        u32 m2pos = sh_bo_hi + (excl >> 16);
        u32 E = totals[0], Tm1 = totals[1], Tm2 = totals[2];
        u64 T = (u64)Tm1 + 2ull * (u64)Tm2;
        float* faces = out + 3ull * E;
        float* uvidx = out + 3ull * E + 3ull * T + (u64)npts2;
        int ci = (z * G + y) * G + x;

#pragma unroll
        for (int w = 0; w < 6; ++w) {
            int ti = ((occ8 >> c_six[w][0]) & 1) | (((occ8 >> c_six[w][1]) & 1) << 1) |
                     (((occ8 >> c_six[w][2]) & 1) << 2) | (((occ8 >> c_six[w][3]) & 1) << 3);
            int nt = c_ntri[ti];
            if (!nt) continue;
            int t = ci * 6 + w;
            for (int tri = 0; tri < nt; ++tri) {
                u64 r = (nt == 1) ? (u64)m1pos : ((u64)Tm1 + 2ull * (u64)m2pos + (u64)tri);
#pragma unroll
                for (int cidx = 0; cidx < 3; ++cidx) {
                    int e = c_tri[ti][3 * tri + cidx];
                    int np_ = c_six[w][(int)c_edge_p[e]];
                    int nq_ = c_six[w][(int)c_edge_q[e]];
                    int lo = np_ < nq_ ? np_ : nq_;
                    int k = (np_ ^ nq_) - 1;  // corners form a bit-subset chain
                    int lonode = v + off[lo];
                    int d0 = (lonode >> 8) - b;
                    int sel = (d0 == 0) ? 0 : (d0 == 1) ? 1 : (d0 == K) ? 2
                              : (d0 == K + 1) ? 3 : 4;
                    u32 vi = sh_vpfx[sel] + (u32)pfx16[lonode] +
                             (u32)__popc((u32)(vmask[lonode] & 0x7Fu) & ((1u << k) - 1u));
                    faces[3ull * r + cidx] = (float)vi;
                }
                uvidx[3ull * r + 0] = (float)(4 * t);
                uvidx[3ull * r + 1] = (float)(4 * t + tri + 1);
                uvidx[3ull * r + 2] = (float)(4 * t + tri + 2);
            }
            if (nt == 1) m1pos++;
            else m2pos++;
        }
        return;
    }
    if (fidx >= 0) {
        // ---------------- crossing-vertex interpolation --------------------
        int vb = fidx - nbV;
        __shared__ u32 sh_vbase;
        {
            int lane = tid & 63, wid = tid >> 6;
            if (wid == 0) {
                u32 r = vpfx_wave(vbsums, coarseV, vb, lane);
                if (lane == 0) sh_vbase = r;
            }
        }
        __syncthreads();
        int v = vb * 256 + tid;
        if (v >= Nv) return;
        u32 m = (u32)(vmask[v] & 0x7Fu);
        if (!m) return;
        u32 r = sh_vbase + (u32)pfx16[v];
        int x = v % V;
        int t2 = v / V;
        int y = t2 % V;
        int z = t2 / V;
        const int V2 = V * V;
        const int d[7]  = {1, V, V + 1, V2, V2 + 1, V2 + V, V2 + V + 1};
        const int dx[7] = {1, 0, 1, 0, 1, 0, 1};
        const int dy[7] = {0, 1, 1, 0, 0, 1, 1};
        const int dz[7] = {0, 0, 0, 1, 1, 1, 1};
        float px = -1.0f + x * h, py = -1.0f + y * h, pz = -1.0f + z * h;
        float s0 = sdf[v];
#pragma unroll
        for (int k = 0; k < 7; ++k) {
            if (m & (1u << k)) {
                float s1 = sdf[v + d[k]];
                float denom = s0 - s1;
                float w0 = -s1 / denom;
                float w1 = s0 / denom;
                out[3ull * r + 0] = px * w0 + (px + dx[k] * h) * w1;
                out[3ull * r + 1] = py * w0 + (py + dy[k] * h) * w1;
                out[3ull * r + 2] = pz * w0 + (pz + dz[k] * h) * w1;
                r++;
            }
        }
        return;
    }
    // ---------------- uvs: one 16B NT store / thread (R10 verified) --------
    int uidx = b0 - min((b0 + 5) / 6, nfront);
    u32 E = totals[0], Tm1 = totals[1], Tm2 = totals[2];
    u64 base = 3ull * E + 3ull * ((u64)Tm1 + 2ull * (u64)Tm2);
    float* uvs = out + base;
    long long head = (long long)((4 - (base & 3)) & 3);
    long long nvec = (npts2 - head) >> 2;  // full 16B stores
    long long t = (long long)uidx * 256 + tid;
    if (t < nvec) {
        long long e0 = head + 4 * t;
        int p = (int)(e0 >> 3);
        int i = (int)((double)p * invN);
        int j = p - i * Nuv;
        if (j >= Nuv) { j -= Nuv; ++i; }
        float tx = (j == Nuv - 1) ? last : (float)((double)j * step_d);
        float ty = (i == Nuv - 1) ? last : (float)((double)i * step_d);
        f32x4 vals;
        int pcur = p;
#pragma unroll
        for (int q = 0; q < 4; ++q) {
            long long e = e0 + q;
            int pe = (int)(e >> 3);
            if (pe != pcur) {
                pcur = pe;
                ++j;
                if (j == Nuv) {
                    j = 0;
                    ++i;
                    ty = (i == Nuv - 1) ? last : (float)((double)i * step_d);
                }
                tx = (j == Nuv - 1) ? last : (float)((double)j * step_d);
            }
            int r = (int)(e & 7);
            int c = r >> 1;
            float vv;
            if ((r & 1) == 0) vv = tx + ((c == 1 || c == 2) ? pad : 0.0f);
            else              vv = ty + ((c >= 2) ? pad : 0.0f);
            vals[q] = vv;
        }
        __builtin_nontemporal_store(vals, (f32x4*)(uvs + e0));
    } else if (t == nvec) {
        for (long long e = 0; e < head; ++e)
            uvs[e] = uv_elem(e, Nuv, invN, step_d, pad, last);
        for (long long e = head + 4 * nvec; e < npts2; ++e)
            uvs[e] = uv_elem(e, Nuv, invN, step_d, pad, last);
    }
}

extern "C" void kernel_launch(void* const* d_in, const int* in_sizes, int n_in,
                              void* d_out, int out_size, void* d_ws, size_t ws_size,
                              hipStream_t stream) {
    const float* sdf = (const float*)d_in[1];
    int Nv = in_sizes[1];
    int F = in_sizes[2] / 4;

    int V = 1;
    while ((long long)V * V * V < (long long)Nv) V++;
    int G = V - 1;

    long long half = (2ll * (long long)F + 1) / 2;
    int Nuv = (int)std::sqrt((double)half);
    while ((long long)Nuv * Nuv < half) Nuv++;
    while (Nuv > 1 && (long long)(Nuv - 1) * (Nuv - 1) >= half) Nuv--;

    int nbV = (Nv + 255) / 256;
    long long npts2 = 2ll * 4ll * (long long)Nuv * (long long)Nuv;

    double invN = 1.0 / (double)Nuv;
    double step_d = (1.0 - invN) / (double)(Nuv - 1);
    float pad = (float)(0.9 * invN);
    float last = (float)(1.0 - invN);

    char* ws = (char*)d_ws;
    size_t off = 0;
    auto walloc = [&](size_t bytes) -> void* {
        void* p = ws + off;
        off = (off + bytes + 255) & ~(size_t)255;
        return p;
    };
    u32* totals  = (u32*)walloc(64);
    u32* vbsums  = (u32*)walloc(sizeof(u32) * (size_t)nbV);
    u32* cbsums  = (u32*)walloc(sizeof(u32) * (size_t)nbV);
    u32* coarseV = (u32*)walloc(sizeof(u32) * 1024);
    u64* coarseC = (u64*)walloc(sizeof(u64) * 1024);
    u8*  vmask   = (u8*)walloc((size_t)Nv);
    u16* pfx16   = (u16*)walloc(sizeof(u16) * (size_t)Nv);
    (void)ws_size;

    float* out = (float*)d_out;
    float h = 2.0f / (float)G;

    long long nthr_uvs = npts2 / 4 + 1;
    int nbU = (int)((nthr_uvs + 255) / 256);
    int nfront = 2 * nbV;
    int nbTail = nbU + nfront;

    hipLaunchKernelGGL(k_main, dim3(nbV), dim3(256), 0, stream, sdf, vmask, pfx16, vbsums,
                       cbsums, Nv, V, G);
    hipLaunchKernelGGL(k_mid, dim3(1), dim3(1024), 0, stream, vbsums, cbsums, nbV, coarseV,
                       coarseC, totals);
    hipLaunchKernelGGL(k_tail, dim3(nbTail), dim3(256), 0, stream, sdf, vmask, pfx16,
                       vbsums, cbsums, coarseV, coarseC, totals, out, Nv, V, G, nbV, h, Nuv,
                       invN, step_d, pad, last, npts2);
}

// Round 17
// 147.618 us; speedup vs baseline: 1.1224x; 1.1224x over previous
//
#include <hip/hip_runtime.h>
#include <cmath>

typedef unsigned int u32;
typedef unsigned long long u64;
typedef unsigned char u8;
typedef unsigned short u16;
typedef float f32x4 __attribute__((ext_vector_type(4)));

// Marching-tets tables from the reference
__constant__ signed char c_tri[16][6] = {
    {-1,-1,-1,-1,-1,-1},
    { 1, 0, 2,-1,-1,-1},
    { 4, 0, 3,-1,-1,-1},
    { 1, 4, 2, 1, 3, 4},
    { 3, 1, 5,-1,-1,-1},
    { 2, 3, 0, 2, 5, 3},
    { 1, 4, 0, 1, 5, 4},
    { 4, 2, 5,-1,-1,-1},
    { 4, 5, 2,-1,-1,-1},
    { 4, 1, 0, 4, 5, 1},
    { 3, 2, 0, 3, 5, 2},
    { 1, 3, 5,-1,-1,-1},
    { 4, 1, 2, 4, 3, 1},
    { 3, 0, 4,-1,-1,-1},
    { 2, 0, 1,-1,-1,-1},
    {-1,-1,-1,-1,-1,-1}};
__constant__ signed char c_ntri[16] = {0,1,1,2,1,2,2,1,1,2,2,1,2,1,1,0};
__constant__ signed char c_edge_p[6] = {0,0,0,1,1,2};
__constant__ signed char c_edge_q[6] = {1,2,3,2,3,3};
// 6-tet decomposition of a cube around the 0-7 diagonal (corner n: bit0=dx,bit1=dy,bit2=dz)
__constant__ u8 c_six[6][4] = {{0,5,1,7},{0,1,3,7},{0,3,2,7},{0,2,6,7},{0,6,4,7},{0,4,5,7}};

// ---- fused pass: mask + occ + cube counts + intra-block prefix (pfx16) ----
// (verified round 9) NO grand-total atomics (round-5 lesson).
__global__ void k_main(const float* __restrict__ sdf, u8* __restrict__ vmask,
                       u16* __restrict__ pfx16, u32* __restrict__ vbsums,
                       u32* __restrict__ cbsums, int Nv, int V, int G) {
    int v = blockIdx.x * 256 + threadIdx.x;
    u32 cnt = 0, pack = 0;
    if (v < Nv) {
        int x = v % V;
        int t = v / V;
        int y = t % V;
        int z = t / V;
        const int V2 = V * V;
        float s0 = sdf[v];
        bool occ0 = s0 > 0.0f;
        bool bx = x < G, by = y < G, bz = z < G;
        int  d[7]  = {1, V, V + 1, V2, V2 + 1, V2 + V, V2 + V + 1};
        bool ok[7] = {bx, by, bx && by, bz, bx && bz, by && bz, bx && by && bz};
        u32 m = 0;
        u32 occ8 = occ0 ? 1u : 0u;
#pragma unroll
        for (int k = 0; k < 7; ++k) {
            if (ok[k]) {
                bool o1 = sdf[v + d[k]] > 0.0f;
                occ8 |= (u32)o1 << (k + 1);
                if (o1 != occ0) m |= (1u << k);
            }
        }
        vmask[v] = (u8)(m | (occ0 ? 0x80u : 0u));
        cnt = __popc(m);
        if (bx && by && bz) {
            u32 c1 = 0, c2 = 0;
#pragma unroll
            for (int w = 0; w < 6; ++w) {
                int ti = ((occ8 >> c_six[w][0]) & 1) | (((occ8 >> c_six[w][1]) & 1) << 1) |
                         (((occ8 >> c_six[w][2]) & 1) << 2) | (((occ8 >> c_six[w][3]) & 1) << 3);
                int nt = c_ntri[ti];
                c1 += (nt == 1);
                c2 += (nt == 2);
            }
            pack = c1 | (c2 << 16);
        }
    }
    int lane = threadIdx.x & 63, wid = threadIdx.x >> 6;
    u32 s = cnt, sp = pack;
#pragma unroll
    for (int o = 1; o < 64; o <<= 1) {
        u32 t = __shfl_up(s, o, 64);
        u32 tp = __shfl_up(sp, o, 64);
        if (lane >= o) { s += t; sp += tp; }
    }
    __shared__ u32 wsum[4], wpk[4];
    if (lane == 63) { wsum[wid] = s; wpk[wid] = sp; }
    __syncthreads();
    u32 wb = 0;
#pragma unroll
    for (int k = 0; k < 4; ++k)
        if (k < wid) wb += wsum[k];
    if (v < Nv) pfx16[v] = (u16)(wb + s - cnt);
    if (threadIdx.x == 0) {
        vbsums[blockIdx.x] = wsum[0] + wsum[1] + wsum[2] + wsum[3];
        cbsums[blockIdx.x] = wpk[0] + wpk[1] + wpk[2] + wpk[3];
    }
}

// ---- scans: 1024 threads x 4 consecutive elems/thread (3 rounds for 8387) -
// block 0: u32 vbsums in place -> totals[0]; block 1: cbsums -> u64 coffs
__global__ void k_scan_both(u32* __restrict__ vbsums, int nV,
                            const u32* __restrict__ cbsums, u64* __restrict__ coffs,
                            int nC, u32* __restrict__ totals) {
    int tid = threadIdx.x;
    int lane = tid & 63, wid = tid >> 6;  // wid in [0,16)
    if (blockIdx.x == 0) {
        __shared__ u32 wsum[16];
        __shared__ u32 carry;
        if (tid == 0) carry = 0;
        __syncthreads();
        for (int start = 0; start < nV; start += 4096) {
            int i0 = start + tid * 4;
            u32 a0 = (i0     < nV) ? vbsums[i0]     : 0u;
            u32 a1 = (i0 + 1 < nV) ? vbsums[i0 + 1] : 0u;
            u32 a2 = (i0 + 2 < nV) ? vbsums[i0 + 2] : 0u;
            u32 a3 = (i0 + 3 < nV) ? vbsums[i0 + 3] : 0u;
            u32 t1 = a0 + a1, t2 = t1 + a2, t3 = t2 + a3;
            u32 v = t3;
#pragma unroll
            for (int o = 1; o < 64; o <<= 1) {
                u32 t = __shfl_up(v, o, 64);
                if (lane >= o) v += t;
            }
            if (lane == 63) wsum[wid] = v;
            __syncthreads();
            if (wid == 0) {
                u32 w = (lane < 16) ? wsum[lane] : 0u;
#pragma unroll
                for (int o = 1; o < 16; o <<= 1) {
                    u32 t = __shfl_up(w, o, 64);
                    if (lane >= o) w += t;
                }
                if (lane < 16) wsum[lane] = w;
            }
            __syncthreads();
            u32 eb = carry + (wid ? wsum[wid - 1] : 0u) + v - t3;
            if (i0     < nV) vbsums[i0]     = eb;
            if (i0 + 1 < nV) vbsums[i0 + 1] = eb + a0;
            if (i0 + 2 < nV) vbsums[i0 + 2] = eb + t1;
            if (i0 + 3 < nV) vbsums[i0 + 3] = eb + t2;
            __syncthreads();
            if (tid == 0) carry += wsum[15];
            __syncthreads();
        }
        if (tid == 0) totals[0] = carry;  // E
    } else {
        __shared__ u64 wsum[16];
        __shared__ u64 carry;
        if (tid == 0) carry = 0;
        __syncthreads();
        for (int start = 0; start < nC; start += 4096) {
            int i0 = start + tid * 4;
            u32 r0 = (i0     < nC) ? cbsums[i0]     : 0u;
            u32 r1 = (i0 + 1 < nC) ? cbsums[i0 + 1] : 0u;
            u32 r2 = (i0 + 2 < nC) ? cbsums[i0 + 2] : 0u;
            u32 r3 = (i0 + 3 < nC) ? cbsums[i0 + 3] : 0u;
            u64 a0 = (u64)(r0 & 0xFFFFu) | ((u64)(r0 >> 16) << 32);
            u64 a1 = (u64)(r1 & 0xFFFFu) | ((u64)(r1 >> 16) << 32);
            u64 a2 = (u64)(r2 & 0xFFFFu) | ((u64)(r2 >> 16) << 32);
            u64 a3 = (u64)(r3 & 0xFFFFu) | ((u64)(r3 >> 16) << 32);
            u64 t1 = a0 + a1, t2 = t1 + a2, t3 = t2 + a3;
            u64 v = t3;
#pragma unroll
            for (int o = 1; o < 64; o <<= 1) {
                u64 t = __shfl_up(v, o, 64);
                if (lane >= o) v += t;
            }
            if (lane == 63) wsum[wid] = v;
            __syncthreads();
            if (wid == 0) {
                u64 w = (lane < 16) ? wsum[lane] : 0ull;
#pragma unroll
                for (int o = 1; o < 16; o <<= 1) {
                    u64 t = __shfl_up(w, o, 64);
                    if (lane >= o) w += t;
                }
                if (lane < 16) wsum[lane] = w;
            }
            __syncthreads();
            u64 eb = carry + (wid ? wsum[wid - 1] : 0ull) + v - t3;
            if (i0     < nC) coffs[i0]     = eb;
            if (i0 + 1 < nC) coffs[i0 + 1] = eb + a0;
            if (i0 + 2 < nC) coffs[i0 + 2] = eb + t1;
            if (i0 + 3 < nC) coffs[i0 + 3] = eb + t2;
            __syncthreads();
            if (tid == 0) carry += wsum[15];
            __syncthreads();
        }
        if (tid == 0) {
            totals[1] = (u32)(carry & 0xFFFFFFFFull);  // Tm1
            totals[2] = (u32)(carry >> 32);            // Tm2
        }
    }
}

// ---- uvs element helper (head/tail scalar path) ---------------------------
__device__ inline float uv_elem(long long e, int Nuv, double invN, double step_d,
                                float pad, float last) {
    int p = (int)(e >> 3);
    int i = (int)((double)p * invN);
    int j = p - i * Nuv;
    if (j >= Nuv) { j -= Nuv; ++i; }
    int r = (int)(e & 7);
    int c = r >> 1;
    if ((r & 1) == 0) {
        float tx = (j == Nuv - 1) ? last : (float)((double)j * step_d);
        return tx + ((c == 1 || c == 2) ? pad : 0.0f);
    }
    float ty = (i == Nuv - 1) ? last : (float)((double)i * step_d);
    return ty + ((c >= 2) ? pad : 0.0f);
}

// ---- TAIL with INTERLEAVED block roles (the R10 optimum: one-shot blocks,
// one 16B NT store per uvs thread, every 6th block is front work) -----------
__global__ void k_tail(const float* __restrict__ sdf, const u8* __restrict__ vmask,
                       const u16* __restrict__ pfx16, const u32* __restrict__ vbsums,
                       const u64* __restrict__ coffs, const u32* __restrict__ totals,
                       float* __restrict__ out, int Nv, int V, int G, int nbV,
                       float h, int Nuv, double invN, double step_d, float pad,
                       float last, long long npts2) {
    int tid = threadIdx.x;
    int b0 = blockIdx.x;
    int nfront = 2 * nbV;
    int fidx = -1;
    if (b0 % 6 == 0) {
        int f = b0 / 6;
        if (f < nfront) fidx = f;
    }
    if (fidx >= 0 && fidx < nbV) {
        // ---------------- faces + uv_idx (verified round-9 body) ----------
        int b = fidx;
        int v = b * 256 + tid;
        const int V2 = V * V;
        u32 pack = 0, occ8 = 0;
        int x = 0, y = 0, z = 0;
        bool interior = false;
        if (v < Nv) {
            x = v % V;
            int t = v / V;
            y = t % V;
            z = t / V;
            interior = (x < G) && (y < G) && (z < G);
        }
        const int off[8] = {0, 1, V, V + 1, V2, V2 + 1, V2 + V, V2 + V + 1};
        if (interior) {
#pragma unroll
            for (int n = 0; n < 8; ++n) occ8 |= (u32)(vmask[v + off[n]] >> 7) << n;
            u32 c1 = 0, c2 = 0;
#pragma unroll
            for (int w = 0; w < 6; ++w) {
                int ti = ((occ8 >> c_six[w][0]) & 1) | (((occ8 >> c_six[w][1]) & 1) << 1) |
                         (((occ8 >> c_six[w][2]) & 1) << 2) | (((occ8 >> c_six[w][3]) & 1) << 3);
                int nt = c_ntri[ti];
                c1 += (nt == 1);
                c2 += (nt == 2);
            }
            pack = c1 | (c2 << 16);
        }
        int lane = tid & 63, wid = tid >> 6;
        u32 s = pack;
#pragma unroll
        for (int o = 1; o < 64; o <<= 1) {
            u32 t = __shfl_up(s, o, 64);
            if (lane >= o) s += t;
        }
        __shared__ u32 wsum[4];
        if (lane == 63) wsum[wid] = s;
        __syncthreads();
        u32 wb = 0;
#pragma unroll
        for (int k = 0; k < 4; ++k)
            if (k < wid) wb += wsum[k];
        u32 excl = wb + s - pack;
        if (!interior || pack == 0) return;

        u64 bo = coffs[b];
        u32 m1pos = (u32)(bo & 0xFFFFFFFFull) + (excl & 0xFFFFu);
        u32 m2pos = (u32)(bo >> 32) + (excl >> 16);
        u32 E = totals[0], Tm1 = totals[1], Tm2 = totals[2];
        u64 T = (u64)Tm1 + 2ull * (u64)Tm2;
        float* faces = out + 3ull * E;
        float* uvidx = out + 3ull * E + 3ull * T + (u64)npts2;
        int ci = (z * G + y) * G + x;

#pragma unroll
        for (int w = 0; w < 6; ++w) {
            int ti = ((occ8 >> c_six[w][0]) & 1) | (((occ8 >> c_six[w][1]) & 1) << 1) |
                     (((occ8 >> c_six[w][2]) & 1) << 2) | (((occ8 >> c_six[w][3]) & 1) << 3);
            int nt = c_ntri[ti];
            if (!nt) continue;
            int t = ci * 6 + w;
            for (int tri = 0; tri < nt; ++tri) {
                u64 r = (nt == 1) ? (u64)m1pos : ((u64)Tm1 + 2ull * (u64)m2pos + (u64)tri);
#pragma unroll
                for (int cidx = 0; cidx < 3; ++cidx) {
                    int e = c_tri[ti][3 * tri + cidx];
                    int np_ = c_six[w][(int)c_edge_p[e]];
                    int nq_ = c_six[w][(int)c_edge_q[e]];
                    int lo = np_ < nq_ ? np_ : nq_;
                    int k = (np_ ^ nq_) - 1;  // corners form a bit-subset chain
                    int lonode = v + off[lo];
                    u32 vi = vbsums[lonode >> 8] + (u32)pfx16[lonode] +
                             (u32)__popc((u32)(vmask[lonode] & 0x7Fu) & ((1u << k) - 1u));
                    faces[3ull * r + cidx] = (float)vi;
                }
                uvidx[3ull * r + 0] = (float)(4 * t);
                uvidx[3ull * r + 1] = (float)(4 * t + tri + 1);
                uvidx[3ull * r + 2] = (float)(4 * t + tri + 2);
            }
            if (nt == 1) m1pos++;
            else m2pos++;
        }
        return;
    }
    if (fidx >= 0) {
        // ---------------- crossing-vertex interpolation (round-9 body) ----
        int vb = fidx - nbV;
        int v = vb * 256 + tid;
        if (v >= Nv) return;
        u32 m = (u32)(vmask[v] & 0x7Fu);
        if (!m) return;
        u32 r = vbsums[vb] + (u32)pfx16[v];
        int x = v % V;
        int t2 = v / V;
        int y = t2 % V;
        int z = t2 / V;
        const int V2 = V * V;
        const int d[7]  = {1, V, V + 1, V2, V2 + 1, V2 + V, V2 + V + 1};
        const int dx[7] = {1, 0, 1, 0, 1, 0, 1};
        const int dy[7] = {0, 1, 1, 0, 0, 1, 1};
        const int dz[7] = {0, 0, 0, 1, 1, 1, 1};
        float px = -1.0f + x * h, py = -1.0f + y * h, pz = -1.0f + z * h;
        float s0 = sdf[v];
#pragma unroll
        for (int k = 0; k < 7; ++k) {
            if (m & (1u << k)) {
                float s1 = sdf[v + d[k]];
                float denom = s0 - s1;
                float w0 = -s1 / denom;
                float w1 = s0 / denom;
                out[3ull * r + 0] = px * w0 + (px + dx[k] * h) * w1;
                out[3ull * r + 1] = py * w0 + (py + dy[k] * h) * w1;
                out[3ull * r + 2] = pz * w0 + (pz + dz[k] * h) * w1;
                r++;
            }
        }
        return;
    }
    // ---------------- uvs: one 16B NT store / thread (R10 verified) -------
    int uidx = b0 - min((b0 + 5) / 6, nfront);
    u32 E = totals[0], Tm1 = totals[1], Tm2 = totals[2];
    u64 base = 3ull * E + 3ull * ((u64)Tm1 + 2ull * (u64)Tm2);
    float* uvs = out + base;
    long long head = (long long)((4 - (base & 3)) & 3);
    long long nvec = (npts2 - head) >> 2;  // full 16B stores
    long long t = (long long)uidx * 256 + tid;
    if (t < nvec) {
        long long e0 = head + 4 * t;
        int p = (int)(e0 >> 3);
        int i = (int)((double)p * invN);
        int j = p - i * Nuv;
        if (j >= Nuv) { j -= Nuv; ++i; }
        float tx = (j == Nuv - 1) ? last : (float)((double)j * step_d);
        float ty = (i == Nuv - 1) ? last : (float)((double)i * step_d);
        f32x4 vals;
        int pcur = p;
#pragma unroll
        for (int q = 0; q < 4; ++q) {
            long long e = e0 + q;
            int pe = (int)(e >> 3);
            if (pe != pcur) {
                pcur = pe;
                ++j;
                if (j == Nuv) {
                    j = 0;
                    ++i;
                    ty = (i == Nuv - 1) ? last : (float)((double)i * step_d);
                }
                tx = (j == Nuv - 1) ? last : (float)((double)j * step_d);
            }
            int r = (int)(e & 7);
            int c = r >> 1;
            float vv;
            if ((r & 1) == 0) vv = tx + ((c == 1 || c == 2) ? pad : 0.0f);
            else              vv = ty + ((c >= 2) ? pad : 0.0f);
            vals[q] = vv;
        }
        __builtin_nontemporal_store(vals, (f32x4*)(uvs + e0));
    } else if (t == nvec) {
        for (long long e = 0; e < head; ++e)
            uvs[e] = uv_elem(e, Nuv, invN, step_d, pad, last);
        for (long long e = head + 4 * nvec; e < npts2; ++e)
            uvs[e] = uv_elem(e, Nuv, invN, step_d, pad, last);
    }
}

extern "C" void kernel_launch(void* const* d_in, const int* in_sizes, int n_in,
                              void* d_out, int out_size, void* d_ws, size_t ws_size,
                              hipStream_t stream) {
    const float* sdf = (const float*)d_in[1];
    int Nv = in_sizes[1];
    int F = in_sizes[2] / 4;

    int V = 1;
    while ((long long)V * V * V < (long long)Nv) V++;
    int G = V - 1;

    long long half = (2ll * (long long)F + 1) / 2;
    int Nuv = (int)std::sqrt((double)half);
    while ((long long)Nuv * Nuv < half) Nuv++;
    while (Nuv > 1 && (long long)(Nuv - 1) * (Nuv - 1) >= half) Nuv--;

    int nbV = (Nv + 255) / 256;
    long long npts2 = 2ll * 4ll * (long long)Nuv * (long long)Nuv;

    double invN = 1.0 / (double)Nuv;
    double step_d = (1.0 - invN) / (double)(Nuv - 1);
    float pad = (float)(0.9 * invN);
    float last = (float)(1.0 - invN);

    char* ws = (char*)d_ws;
    size_t off = 0;
    auto walloc = [&](size_t bytes) -> void* {
        void* p = ws + off;
        off = (off + bytes + 255) & ~(size_t)255;
        return p;
    };
    u32* totals = (u32*)walloc(64);
    u32* vbsums = (u32*)walloc(sizeof(u32) * (size_t)nbV);
    u32* cbsums = (u32*)walloc(sizeof(u32) * (size_t)nbV);
    u64* coffs  = (u64*)walloc(sizeof(u64) * (size_t)nbV);
    u8*  vmask  = (u8*)walloc((size_t)Nv);
    u16* pfx16  = (u16*)walloc(sizeof(u16) * (size_t)Nv);
    (void)ws_size;

    float* out = (float*)d_out;
    float h = 2.0f / (float)G;

    long long nthr_uvs = npts2 / 4 + 1;
    int nbU = (int)((nthr_uvs + 255) / 256);
    int nfront = 2 * nbV;
    int nbTail = nbU + nfront;

    hipLaunchKernelGGL(k_main, dim3(nbV), dim3(256), 0, stream, sdf, vmask, pfx16, vbsums,
                       cbsums, Nv, V, G);
    hipLaunchKernelGGL(k_scan_both, dim3(2), dim3(1024), 0, stream, vbsums, nbV, cbsums, coffs,
                       nbV, totals);
    hipLaunchKernelGGL(k_tail, dim3(nbTail), dim3(256), 0, stream, sdf, vmask, pfx16,
                       vbsums, coffs, totals, out, Nv, V, G, nbV, h, Nuv, invN, step_d, pad,
                       last, npts2);
}